// Round 22
// baseline (37.787 us; speedup 1.0000x reference)
//
#include <hip/hip_runtime.h>

#define TPB  256     // 4 waves; 2-slab in-block pipeline, 4-branch FK per slab
#define RPS  64      // rows per slab, one per lane
#define XDIM 99
#define NJ   26
#define OUTW 78
#define SLABF (RPS * XDIM)   // 6336 floats = 25344 B

// slot tables (slot 0 = hip, slots 1..25 follow ORDER)
constexpr int OFF_IDX[NJ] = {0,1,2,3,4,6,7,8,9,11,12,13,14,15,16,17,18,19,20,22,24,25,26,27,28,30};
constexpr int PAR[NJ]     = {-1,0,1,2,3,0,5,6,7,0,9,10,11,12,10,14,15,16,17,17,10,20,21,22,23,23};

__device__ __forceinline__ float fast_rcp(float a)  { return __builtin_amdgcn_rcpf(a); }
__device__ __forceinline__ float fast_sqrt(float a) { return __builtin_amdgcn_sqrtf(a); }

__device__ __forceinline__ void rodrigues(float ax, float ay, float az, float* R) {
    const float EPS = 1.1920928955078125e-07f;   // np.finfo(np.float32).eps
    float t = fast_sqrt(ax*ax + ay*ay + az*az);
    float inv = fast_rcp(t + EPS);
    float r0 = ax*inv, r1 = ay*inv, r2 = az*inv;
    float s, c;
    __sincosf(t, &s, &c);
    float omc = 1.0f - c;
    float r00 = r0*r0, r11 = r1*r1, r22 = r2*r2;
    float r01 = r0*r1, r02 = r0*r2, r12 = r1*r2;
    R[0] = 1.0f - omc*(r11 + r22);
    R[1] = -s*r2 + omc*r01;
    R[2] =  s*r1 + omc*r02;
    R[3] =  s*r2 + omc*r01;
    R[4] = 1.0f - omc*(r00 + r22);
    R[5] = -s*r0 + omc*r12;
    R[6] = -s*r1 + omc*r02;
    R[7] =  s*r0 + omc*r12;
    R[8] = 1.0f - omc*(r00 + r11);
}

#define STEP(s) do {                                                          \
    const int i_  = OFF_IDX[(s)];                                             \
    const int pa_ = PAR[(s)];                                                 \
    float L[9];                                                               \
    rodrigues(row[3*i_+3], row[3*i_+4], row[3*i_+5], L);                      \
    const float o0 = off[3*i_], o1 = off[3*i_+1], o2 = off[3*i_+2];           \
    _Pragma("unroll")                                                         \
    for (int c = 0; c < 3; ++c)                                               \
        pp[(s)][c] = o0*ang[pa_][c] + o1*ang[pa_][3+c] + o2*ang[pa_][6+c]     \
                   + pp[pa_][c];                                              \
    _Pragma("unroll")                                                         \
    for (int j = 0; j < 3; ++j)                                               \
        _Pragma("unroll")                                                     \
        for (int kk = 0; kk < 3; ++kk)                                        \
            ang[(s)][3*j+kk] = L[3*j+0]*ang[pa_][0+kk]                        \
                             + L[3*j+1]*ang[pa_][3+kk]                        \
                             + L[3*j+2]*ang[pa_][6+kk];                       \
} while (0)

// issue one slab's DMA, 4-way wave split (R21-proven): wave w -> 6 x 16B ops,
// waves 1..3 also one 4B tail op. Per-wave op count: w0=6, w1..3=7.
__device__ __forceinline__ void dma_slab(const float* gsrc, float* lbuf, int w, int l) {
    #pragma unroll
    for (int j = 0; j < 6; ++j) {
        const int jj = 6 * w + j;
        __builtin_amdgcn_global_load_lds(
            (const __attribute__((address_space(1))) unsigned int*)(gsrc + 256*jj + 4*l),
            (__attribute__((address_space(3))) unsigned int*)(lbuf + 256*jj),
            16, 0, 0);
    }
    if (w >= 1) {
        const int kk = w - 1;
        __builtin_amdgcn_global_load_lds(
            (const __attribute__((address_space(1))) unsigned int*)(gsrc + 6144 + 64*kk + l),
            (__attribute__((address_space(3))) unsigned int*)(lbuf + 6144 + 64*kk),
            4, 0, 0);
    }
}

// compute 4-branch FK on one slab + pack into the (dead) slab + linear flush.
__device__ __forceinline__ void process_slab(float* slab, float* ob,
                                             const float* __restrict__ off,
                                             int t, int w, int l) {
    const float* row = &slab[l * XDIM];          // stride 99 -> conflict-free
    float ang[NJ][9];
    float pp[NJ][3];

    {   // hip (trunk root, all waves)
        float R[9];
        rodrigues(row[3], row[4], row[5], R);
        #pragma unroll
        for (int q = 0; q < 9; ++q) ang[0][q] = R[q];
        pp[0][0] = off[0] + row[0];
        pp[0][1] = off[1] + row[1];
        pp[0][2] = off[2] + row[2];
    }
    if (w == 0) {                                // both legs: slots 1..8
        #pragma unroll
        for (int s = 1; s <= 8; ++s) STEP(s);
    } else if (w == 1) {                         // spine+head: slots 9..13
        #pragma unroll
        for (int s = 9; s <= 13; ++s) STEP(s);
    } else if (w == 2) {                         // left arm: 9,10 + 14..19
        STEP(9); STEP(10);
        #pragma unroll
        for (int s = 14; s <= 19; ++s) STEP(s);
    } else {                                     // right arm: 9,10 + 20..25
        STEP(9); STEP(10);
        #pragma unroll
        for (int s = 20; s <= 25; ++s) STEP(s);
    }

    // all waves done reading this slab before pack overwrites it
    asm volatile("s_waitcnt lgkmcnt(0)" ::: "memory");
    __builtin_amdgcn_s_barrier();

    {   // pack pos at stride 78, wave-disjoint column ranges
        float* srow = &slab[l * OUTW];
        if (w == 0) {
            #pragma unroll
            for (int s = 1; s <= 8; ++s) {
                srow[3*s+0] = pp[s][0]; srow[3*s+1] = pp[s][1]; srow[3*s+2] = pp[s][2];
            }
        } else if (w == 1) {
            srow[0] = pp[0][0]; srow[1] = pp[0][1]; srow[2] = pp[0][2];
            #pragma unroll
            for (int s = 9; s <= 13; ++s) {
                srow[3*s+0] = pp[s][0]; srow[3*s+1] = pp[s][1]; srow[3*s+2] = pp[s][2];
            }
        } else if (w == 2) {
            #pragma unroll
            for (int s = 14; s <= 19; ++s) {
                srow[3*s+0] = pp[s][0]; srow[3*s+1] = pp[s][1]; srow[3*s+2] = pp[s][2];
            }
        } else {
            #pragma unroll
            for (int s = 20; s <= 25; ++s) {
                srow[3*s+0] = pp[s][0]; srow[3*s+1] = pp[s][1]; srow[3*s+2] = pp[s][2];
            }
        }
    }
    asm volatile("s_waitcnt lgkmcnt(0)" ::: "memory");
    __builtin_amdgcn_s_barrier();                // packed slab visible to all 256

    {   // flush: pure linear copy, 1248 float4, full lines, single touch
        float4* ob4 = reinterpret_cast<float4*>(ob);
        const float4* b4 = reinterpret_cast<const float4*>(slab);
        #pragma unroll
        for (int j = 0; j < 4; ++j)              // 4*256 = 1024
            ob4[t + 256*j] = b4[t + 256*j];
        if (t < 224) ob4[1024 + t] = b4[1024 + t];
    }
}

// (256,3): VGPR cap ~170 (R21 path ~76). LDS 50688B -> 3 blocks/CU = 12 waves.
__global__ __launch_bounds__(TPB, 3) void skel_fk(const float* __restrict__ x,
                                                  const float* __restrict__ off,
                                                  float* __restrict__ out) {
    __shared__ __align__(16) float buf[2][SLABF];     // 2 x 25344 B
    const int t = threadIdx.x;
    const int w = t >> 6;                        // wave id 0..3 (uniform)
    const int l = t & 63;                        // lane = row
    const int row0 = blockIdx.x * (2 * RPS);     // 128 rows per block
    const float* gA = x + (long long)row0 * XDIM;
    const float* gB = gA + SLABF;
    float* oA = out + (long long)row0 * OUTW;
    float* oB = oA + RPS * OUTW;

    // issue BOTH slabs' DMA up front (per wave: 6-7 A-ops then 6-7 B-ops)
    dma_slab(gA, buf[0], w, l);
    dma_slab(gB, buf[1], w, l);

    // wait own slab-A ops only (vmcnt counted per wave; B stays in flight);
    // vmcnt(6): w0 leaves exactly its 6 B-ops; w1..3 over-wait one B-op (safe).
    asm volatile("s_waitcnt vmcnt(6)" ::: "memory");
    __builtin_amdgcn_s_barrier();                // all waves' A data resident

    process_slab(buf[0], oA, off, t, w, l);      // slab B streams in under this

    // wait slab-B loads: outstanding = B-loads (oldest) + flush-A stores (<=5,
    // newest). vmcnt(5) -> all B-loads retired; stores may stay in flight.
    asm volatile("s_waitcnt vmcnt(5)" ::: "memory");
    __builtin_amdgcn_s_barrier();                // all waves' B data resident

    process_slab(buf[1], oB, off, t, w, l);
}

extern "C" void kernel_launch(void* const* d_in, const int* in_sizes, int n_in,
                              void* d_out, int out_size, void* d_ws, size_t ws_size,
                              hipStream_t stream) {
    const float* x   = (const float*)d_in[0];
    const float* off = (const float*)d_in[1];
    float* out = (float*)d_out;
    const int B = in_sizes[0] / XDIM;      // 262144
    const int grid = B / (2 * RPS);        // 2048
    skel_fk<<<grid, TPB, 0, stream>>>(x, off, out);
}